// Round 15
// baseline (198.591 us; speedup 1.0000x reference)
//
#include <hip/hip_runtime.h>

// B=2, L=2048, D=1024, H=16, HD=64.  All matmuls via bf16 MFMA (fp32 accum).
#define Bc 2
#define Lc 2048
#define Dc 1024
#define Hc 16
#define HDc 64
#define LOG2E 1.44269504088896340736f

typedef __bf16 bf16x8 __attribute__((ext_vector_type(8)));
typedef __bf16 bf16x2 __attribute__((ext_vector_type(2)));
typedef float f32x4 __attribute__((ext_vector_type(4)));
typedef unsigned short u16;
typedef unsigned int u32;
typedef unsigned long long u64;

// fp32 -> bf16 round-to-nearest-even
__device__ __forceinline__ u16 f2bf(float x) {
    union { float f; u32 u; } c; c.f = x;
    u32 u = c.u + 0x7fffu + ((c.u >> 16) & 1u);
    return (u16)(u >> 16);
}

// pack two fp32 -> bf16x2 in one u32 (low = a)
__device__ __forceinline__ u32 pkbf(float a, float b) {
#if __has_builtin(__builtin_amdgcn_cvt_pk_bf16_f32)
    union { bf16x2 v; u32 u; } c;
    c.v = __builtin_amdgcn_cvt_pk_bf16_f32(a, b);
    return c.u;
#else
    return (u32)f2bf(a) | ((u32)f2bf(b) << 16);
#endif
}

// raw v_exp_f32 (2^x); libm exp2f adds denormal-range scaffolding we don't
// need (denormal p == 0 for softmax purposes).
__device__ __forceinline__ float fexp2(float x) {
#if __has_builtin(__builtin_amdgcn_exp2f)
    return __builtin_amdgcn_exp2f(x);
#else
    return exp2f(x);
#endif
}

// async global->LDS, 16B/lane. LDS dest = wave-uniform base + lane*16 (m104).
__device__ __forceinline__ void g2l16(const void* g, void* l) {
    __builtin_amdgcn_global_load_lds(
        (const __attribute__((address_space(1))) void*)g,
        (__attribute__((address_space(3))) void*)l, 16, 0, 0);
}

// ---------------------------------------------------------------------------
// cast fp32 -> bf16: query (4096x1024) + Wq/Wk/Wv/Wo (1024x1024 each)
// ---------------------------------------------------------------------------
__global__ __launch_bounds__(256) void cast_bf16(
    const float* __restrict__ x,
    const float* __restrict__ wq, const float* __restrict__ wk,
    const float* __restrict__ wv, const float* __restrict__ wo,
    u16* __restrict__ xb, u16* __restrict__ wqb, u16* __restrict__ wkb,
    u16* __restrict__ wvb, u16* __restrict__ wob)
{
    const int i = blockIdx.x * 256 + threadIdx.x;   // float4 index
    const float* s; u16* d; int off;
    if (i < 1048576) { s = x; d = xb; off = i; }
    else {
        const int j = i - 1048576;
        const int sel = j >> 18;            // 0..3
        off = j & 262143;
        s = sel == 0 ? wq : sel == 1 ? wk : sel == 2 ? wv : wo;
        d = sel == 0 ? wqb : sel == 1 ? wkb : sel == 2 ? wvb : wob;
    }
    const float4 f = ((const float4*)s)[off];
    ushort4 o;
    o.x = f2bf(f.x); o.y = f2bf(f.y); o.z = f2bf(f.z); o.w = f2bf(f.w);
    ((ushort4*)d)[off] = o;
}

// ---------------------------------------------------------------------------
// R22 body: 64(A-rows) x 64(B-rows) tile, BK=64, XOR-swizzled g2l16 staging.
// LDS 16KB, 16 chunks (4/wave), 4 waves 2x2 over the tile, acc[2][2]
// (16 VGPR -- no spill risk). Proven in gemm_o (R22, refcheck'd); now also
// used by all three qkv planes (R23): occupancy ladder's last rung
// (R15/R20/R22 precedent: residency dominates staging amortization here).
// ---------------------------------------------------------------------------
__device__ __forceinline__ void gemm_oo_body(
    const u16* __restrict__ A, const u16* __restrict__ Bm,
    int row0, int col0, int K,
    f32x4 (&acc)[2][2], u16* As, u16* Bs)
{
    const int tid  = threadIdx.x;
    const int w    = tid >> 6;
    const int lane = tid & 63;
    const int l15  = lane & 15, quad = lane >> 4;
    const int srow = lane >> 3;
    const int sxor = ((lane & 7) ^ srow) << 3;
    const int wm   = (w & 1) << 5, wn = (w >> 1) << 5;   // 2x2 waves over 64x64
    const int l7   = l15 & 7;

    for (int k0 = 0; k0 < K; k0 += 64) {
        __syncthreads();
#pragma unroll
        for (int s = 0; s < 4; ++s) {      // 16 chunks: 8 A (64 rows) + 8 B (64)
            const int c = w * 4 + s;       // 0..15 (wave-uniform branch)
            if (c < 8) {
                const int rb = c * 8;
                g2l16(&A [(size_t)(row0 + rb + srow) * K + k0 + sxor], &As[rb * 64]);
            } else {
                const int rb = (c - 8) * 8;
                g2l16(&Bm[(size_t)(col0 + rb + srow) * K + k0 + sxor], &Bs[rb * 64]);
            }
        }
        __syncthreads();

#pragma unroll
        for (int kk = 0; kk < 2; ++kk) {
            bf16x8 af[2], bf[2];
#pragma unroll
            for (int i = 0; i < 2; ++i)
                af[i] = *(const bf16x8*)&As[(wm + i * 16 + l15) * 64 +
                                            (((kk * 4 + quad) ^ l7) << 3)];
#pragma unroll
            for (int j = 0; j < 2; ++j)
                bf[j] = *(const bf16x8*)&Bs[(wn + j * 16 + l15) * 64 +
                                            (((kk * 4 + quad) ^ l7) << 3)];
#pragma unroll
            for (int i = 0; i < 2; ++i)
#pragma unroll
                for (int j = 0; j < 2; ++j)
                    acc[i][j] = __builtin_amdgcn_mfma_f32_16x16x32_bf16(
                        af[i], bf[j], acc[i][j], 0, 0, 0);
        }
    }
}

// ---------------------------------------------------------------------------
// Fused QKV projection, R23: 64x64 tiles via gemm_oo_body. grid (64, 16, 3)
// = 3072 blocks = 12/CU requested, ~8/CU resident (LDS 16KB cap 10, wave
// cap 32/4=8; was 6/CU at 128x64).
//   q/k (z=0/1), SWAPPED (A=W 64 feat, B=X 64 tok): y=feat-tile(16),
//        x=tok-tile(64). h = row0>>6; hd = wm + i*16 + quad*4 (i<2).
//   v (z=2), NORMAL (A=X 64 tok, B=Wv 64 feat): x=tok-tile, y=feat-tile.
// q: *(0.125*log2e) folded (exp2-domain softmax).
// Pre-committed read: total >= 191.5 => ladder exhausted, revert to R22.
// ---------------------------------------------------------------------------
__global__ __launch_bounds__(256) void gemm_qkv_bf16(
    const u16* __restrict__ Xb,
    const u16* __restrict__ Wqb, const u16* __restrict__ Wkb, const u16* __restrict__ Wvb,
    const float* __restrict__ bq, const float* __restrict__ bk, const float* __restrict__ bv,
    u16* __restrict__ qo, u16* __restrict__ ko, u16* __restrict__ vto)
{
    __shared__ __attribute__((aligned(16))) u16 As[64 * 64];
    __shared__ __attribute__((aligned(16))) u16 Bs[64 * 64];

    const int z = blockIdx.z;
    const int tid = threadIdx.x;
    const int w = tid >> 6, lane = tid & 63;
    const int l15 = lane & 15, quad = lane >> 4;
    const int wm = (w & 1) << 5, wn = (w >> 1) << 5;

    f32x4 acc[2][2];
#pragma unroll
    for (int i = 0; i < 2; ++i)
#pragma unroll
        for (int j = 0; j < 2; ++j)
#pragma unroll
            for (int r = 0; r < 4; ++r) acc[i][j][r] = 0.0f;

    if (z == 2) {
        // ---- v, NORMAL: A = X (64 tokens), B = Wv (64 features) ----
        const int row0 = blockIdx.x << 6;      // token tile
        const int col0 = blockIdx.y << 6;      // feature tile
        gemm_oo_body(Xb, Wvb, row0, col0, Dc, acc, As, Bs);

        const int b = row0 >> 11;              // 64-tile never crosses b
#pragma unroll
        for (int j = 0; j < 2; ++j) {
            const int n = col0 + wn + j * 16 + l15;   // feature
            const float bj = bv[n];
            const int hh = n >> 6, hd = n & 63;
            u16* vbase = vto + (((size_t)(b * Hc + hh) * HDc + hd) << 11);
#pragma unroll
            for (int i = 0; i < 2; ++i) {
                const int l = (row0 + wm + i * 16 + quad * 4) & (Lc - 1);
                uint2 pr;
                pr.x = pkbf(acc[i][j][0] + bj, acc[i][j][1] + bj);
                pr.y = pkbf(acc[i][j][2] + bj, acc[i][j][3] + bj);
                *(uint2*)&vbase[l] = pr;
            }
        }
        return;
    }

    // ---- q/k, SWAPPED: A = W (64 features), B = X (64 tokens) ----
    const u16*   W    = z == 0 ? Wqb : Wkb;
    const float* bias = z == 0 ? bq  : bk;
    u16*         outp = z == 0 ? qo  : ko;
    const int row0 = blockIdx.y << 6;          // feature tile (64)
    const int col0 = blockIdx.x << 6;          // token tile (64)
    gemm_oo_body(W, Xb, row0, col0, Dc, acc, As, Bs);

    const float qs = z == 0 ? 0.125f * LOG2E : 1.0f;   // HD^-0.5 * log2(e)
    const int h = row0 >> 6;                   // head const per block (64-aligned)
    float4 b4[2];
#pragma unroll
    for (int i = 0; i < 2; ++i)
        b4[i] = *(const float4*)&bias[row0 + wm + i * 16 + quad * 4];

#pragma unroll
    for (int j = 0; j < 2; ++j) {
        const int tok = col0 + wn + j * 16 + l15;
        const int bb = tok >> 11, ll = tok & (Lc - 1);
        u16* obase = outp + (((size_t)(bb * Hc + h) * Lc + ll) << 6);
#pragma unroll
        for (int i = 0; i < 2; ++i) {
            uint2 pr;
            pr.x = pkbf((acc[i][j][0] + b4[i].x) * qs, (acc[i][j][1] + b4[i].y) * qs);
            pr.y = pkbf((acc[i][j][2] + b4[i].z) * qs, (acc[i][j][3] + b4[i].w) * qs);
            *(uint2*)&obase[wm + i * 16 + quad * 4] = pr;   // hd = wm+i*16+quad*4
        }
    }
}

// ---------------------------------------------------------------------------
// Flash attention, S^T formulation, max-free softmax.  R14 (session best,
// 57us). 8-wave blocks (512 thr), 128 q-rows/block, single-buffer 34KB LDS,
// grid 512. Waves {0-3}: q-sub wq=w&3, key-half 0; waves {4-7}: same q
// rows, key-half 1 (hf=w>>2). Epilogue: 4 wave-pair combine via LDS.
// Falsified alternatives (do not revisit): dbuf staging (R13 69us),
// 64-row grid split (R17 65us), direct-L2 no-LDS (R16 181us), addr hoist
// (R18 72us), KVBLK=256 (R19 72us), fused q+k spill (R21, qkv 101us).
// ---------------------------------------------------------------------------
__global__ __launch_bounds__(512) void attn_mfma(
    const u16* __restrict__ q, const u16* __restrict__ k,
    const u16* __restrict__ vt, u16* __restrict__ out)
{
    // Manually carved LDS: Ks 16KB | Vs 16KB | cl 2KB = 34KB.
    // Epilogue overlays co (32KB floats) on Ks+Vs.
    __shared__ __attribute__((aligned(16))) u16 smem[17408];
    u16* Ks0 = smem;            // [2 d-panels][128 j][32 d] (p*4096 + j*32)
    u16* Vs0 = smem + 8192;     // [4 j-panels][64 d][32 j]  (cp*2048 + d*32)

    const int tid = threadIdx.x;
    const int w = tid >> 6, lane = tid & 63;
    const int l15 = lane & 15, quad = lane >> 4;
    const int bh = blockIdx.x & 31;          // bh fastest: same-bh -> same XCD
    const int qt = blockIdx.x >> 5;          // 0..15
    const int h  = bh & (Hc - 1);
    const int b  = bh >> 4;
    const int l0 = qt << 7;                  // 128 q-rows per block
    const int wq = w & 3;                    // q-row sub-block (32 rows)
    const int hf = w >> 2;                   // fixed 64-key half of staged tile

    const size_t bhs = (size_t)(b * Hc + h) * (Lc * HDc);
    const u16* qb = q  + bhs;
    const u16* kb = k  + bhs;
    const u16* vb = vt + bhs;            // [HD][L]

    bf16x8 qf[2][2];
#pragma unroll
    for (int mt = 0; mt < 2; ++mt) {
        const size_t row = (size_t)(l0 + wq * 32 + mt * 16 + l15) * HDc;
        qf[mt][0] = *(const bf16x8*)&qb[row + quad * 8];
        qf[mt][1] = *(const bf16x8*)&qb[row + 32 + quad * 8];
    }

    const int srow  = lane >> 2;
    const int sunit = lane & 3;
    const int gd = (l15 >> 1) & 3;

    f32x4 oacc[2][4];
    float l_i[2] = {0.0f, 0.0f};
#pragma unroll
    for (int mt = 0; mt < 2; ++mt)
#pragma unroll
        for (int dt = 0; dt < 4; ++dt)
#pragma unroll
            for (int r = 0; r < 4; ++r) oacc[mt][dt][r] = 0.0f;

    for (int kt = 0; kt < Lc; kt += 128) {
        __syncthreads();
        // stage K (16KB: 2 d-panels x 8 groups) + V (16KB: 4 j-panels x 4
        // groups) = 32 chunks, 4 per wave; XOR swizzle on global source.
#pragma unroll
        for (int i = 0; i < 4; ++i) {
            const int c = w * 4 + i;             // 0..31
            if (c < 16) {     // K chunk: row = key j in tile (0..127)
                const int p = c >> 3, g = c & 7;
                const int row = g * 16 + srow;
                g2l16(&kb[(size_t)(kt + row) * HDc + p * 32 +
                          ((sunit ^ ((row >> 1) & 3)) << 3)],
                      &Ks0[p * 4096 + g * 512]);
            } else {          // V chunk: row = d (0..63)
                const int cc = c - 16;
                const int cp = cc >> 2, g = cc & 3;
                const int row = g * 16 + srow;
                g2l16(&vb[(size_t)row * Lc + kt + cp * 32 +
                          ((sunit ^ ((row >> 1) & 3)) << 3)],
                      &Vs0[cp * 2048 + g * 512]);
            }
        }
        __syncthreads();

        // ---- one 64-key half (hf fixed per wave; R12 inner body) ----
        f32x4 st[2][4];
        __builtin_amdgcn_s_setprio(1);
#pragma unroll
        for (int t = 0; t < 4; ++t) {
            const int j   = (hf * 4 + t) * 16 + l15;
            const int off = j * 32 + ((quad ^ gd) << 3);
            const bf16x8 kf0 = *(const bf16x8*)&Ks0[off];
            const bf16x8 kf1 = *(const bf16x8*)&Ks0[4096 + off];
#pragma unroll
            for (int mt = 0; mt < 2; ++mt) {
                f32x4 z = {0.0f, 0.0f, 0.0f, 0.0f};
                z = __builtin_amdgcn_mfma_f32_16x16x32_bf16(kf0, qf[mt][0], z, 0, 0, 0);
                st[mt][t] = __builtin_amdgcn_mfma_f32_16x16x32_bf16(kf1, qf[mt][1], z, 0, 0, 0);
            }
        }
        __builtin_amdgcn_s_setprio(0);

        u32 pk[2][4][2];
#pragma unroll
        for (int mt = 0; mt < 2; ++mt) {
            f32x4 s4 = {0.0f, 0.0f, 0.0f, 0.0f};
#pragma unroll
            for (int t = 0; t < 4; ++t) {
                f32x4 p;
#pragma unroll
                for (int r = 0; r < 4; ++r) p[r] = fexp2(st[mt][t][r]);
                s4 += p;
                pk[mt][t][0] = pkbf(p[0], p[1]);
                pk[mt][t][1] = pkbf(p[2], p[3]);
            }
            l_i[mt] += s4[0] + s4[1] + s4[2] + s4[3];
        }

        __builtin_amdgcn_s_setprio(1);
#pragma unroll
        for (int cpl = 0; cpl < 2; ++cpl) {
            const int cp = hf * 2 + cpl;     // V panel (j-chunks 2cp,2cp+1)
            union { bf16x8 v; u32 uw[4]; } pf0, pf1;
            pf0.uw[0] = pk[0][2 * cpl][0];     pf0.uw[1] = pk[0][2 * cpl][1];
            pf0.uw[2] = pk[0][2 * cpl + 1][0]; pf0.uw[3] = pk[0][2 * cpl + 1][1];
            pf1.uw[0] = pk[1][2 * cpl][0];     pf1.uw[1] = pk[1][2 * cpl][1];
            pf1.uw[2] = pk[1][2 * cpl + 1][0]; pf1.uw[3] = pk[1][2 * cpl + 1][1];
#pragma unroll
            for (int dt = 0; dt < 4; ++dt) {
                const int base = cp * 2048 + (dt * 16 + l15) * 32 + ((quad & 1) << 2);
                union { bf16x8 v; u64 d[2]; } vf;
                vf.d[0] = *(const u64*)&Vs0[base + (((quad >> 1) ^ gd) << 3)];
                vf.d[1] = *(const u64*)&Vs0[base + (((2 + (quad >> 1)) ^ gd) << 3)];
                oacc[0][dt] = __builtin_amdgcn_mfma_f32_16x16x32_bf16(
                    vf.v, pf0.v, oacc[0][dt], 0, 0, 0);
                oacc[1][dt] = __builtin_amdgcn_mfma_f32_16x16x32_bf16(
                    vf.v, pf1.v, oacc[1][dt], 0, 0, 0);
            }
        }
        __builtin_amdgcn_s_setprio(0);
    }

    // ---- cross-pair combine: waves 4-7 hand their key-half partials to
    // waves 0-3 (same q rows, other 64-key half). Max-free softmax => plain
    // elementwise add. co overlays Ks+Vs (32KB exactly: 32 floats x 256
    // lanes, [idx][base] stride-256 = conflict-free b32); cl = 2KB tail.
    __syncthreads();                         // all waves done with tile LDS
    float* co = (float*)smem;
    float* cl = (float*)(smem + 16384);
    if (w >= 4) {
        const int base = (w - 4) * 64 + lane;          // 0..255
#pragma unroll
        for (int mt = 0; mt < 2; ++mt)
#pragma unroll
            for (int dt = 0; dt < 4; ++dt)
#pragma unroll
                for (int r = 0; r < 4; ++r)
                    co[(mt * 16 + dt * 4 + r) * 256 + base] = oacc[mt][dt][r];
        cl[base]       = l_i[0];
        cl[256 + base] = l_i[1];
    }
    __syncthreads();
    if (w >= 4) return;
    {
        const int base = w * 64 + lane;                // 0..255
#pragma unroll
        for (int mt = 0; mt < 2; ++mt)
#pragma unroll
            for (int dt = 0; dt < 4; ++dt)
#pragma unroll
                for (int r = 0; r < 4; ++r)
                    oacc[mt][dt][r] += co[(mt * 16 + dt * 4 + r) * 256 + base];
        l_i[0] += cl[base];
        l_i[1] += cl[256 + base];
    }

#pragma unroll
    for (int mt = 0; mt < 2; ++mt) {
        float l = l_i[mt];
        l += __shfl_xor(l, 16);
        l += __shfl_xor(l, 32);
        const float inv = 1.0f / l;
        const int lrow = l0 + wq * 32 + mt * 16 + l15;
        u16* ob = out + ((size_t)(b * Lc + lrow)) * Dc + h * HDc;
#pragma unroll
        for (int dt = 0; dt < 4; ++dt) {
            uint2 pr;
            pr.x = pkbf(oacc[mt][dt][0] * inv, oacc[mt][dt][1] * inv);
            pr.y = pkbf(oacc[mt][dt][2] * inv, oacc[mt][dt][3] * inv);
            *(uint2*)&ob[dt * 16 + quad * 4] = pr;
        }
    }
}

// ---------------------------------------------------------------------------
// Output projection, R22 (frozen): 64(feature) x 64(token) tiles, grid
// (64, 16) = 1024 blocks = 4 blocks/CU. LDS 16KB. SWAPPED: regs run along
// features -> float4 contiguous stores into row-major (B,L,D) fp32.
// ---------------------------------------------------------------------------
__global__ __launch_bounds__(256) void gemm_o_bf16(
    const u16* __restrict__ Ab, const u16* __restrict__ Wob,
    const float* __restrict__ bo, float* __restrict__ out)
{
    __shared__ __attribute__((aligned(16))) u16 As[64 * 64];
    __shared__ __attribute__((aligned(16))) u16 Bs[64 * 64];
    const int row0 = blockIdx.y << 6;          // feature tile (64)
    const int col0 = blockIdx.x << 6;          // token tile (64)

    f32x4 acc[2][2];
#pragma unroll
    for (int i = 0; i < 2; ++i)
#pragma unroll
        for (int j = 0; j < 2; ++j)
#pragma unroll
            for (int r = 0; r < 4; ++r) acc[i][j][r] = 0.0f;

    gemm_oo_body(Wob, Ab, row0, col0, Dc, acc, As, Bs);

    const int tid = threadIdx.x;
    const int w = tid >> 6, lane = tid & 63;
    const int l15 = lane & 15, quad = lane >> 4;
    const int wm = (w & 1) << 5, wn = (w >> 1) << 5;

    float4 b4[2];
#pragma unroll
    for (int i = 0; i < 2; ++i)
        b4[i] = *(const float4*)&bo[row0 + wm + i * 16 + quad * 4];

#pragma unroll
    for (int j = 0; j < 2; ++j) {
        const int tok = col0 + wn + j * 16 + l15;
        float* obase = out + (size_t)tok * Dc + row0 + wm;
#pragma unroll
        for (int i = 0; i < 2; ++i) {
            float4 o;
            o.x = acc[i][j][0] + b4[i].x; o.y = acc[i][j][1] + b4[i].y;
            o.z = acc[i][j][2] + b4[i].z; o.w = acc[i][j][3] + b4[i].w;
            *(float4*)&obase[i * 16 + quad * 4] = o;
        }
    }
}

extern "C" void kernel_launch(void* const* d_in, const int* in_sizes, int n_in,
                              void* d_out, int out_size, void* d_ws, size_t ws_size,
                              hipStream_t stream)
{
    const float* query = (const float*)d_in[0];
    const float* Wq = (const float*)d_in[1];
    const float* bq = (const float*)d_in[2];
    const float* Wk = (const float*)d_in[3];
    const float* bk = (const float*)d_in[4];
    const float* Wv = (const float*)d_in[5];
    const float* bv = (const float*)d_in[6];
    const float* Wo = (const float*)d_in[7];
    const float* bo = (const float*)d_in[8];

    // ws layout (u16 elems): xb 4.19M | wq/wk/wv/wo 1.05M ea | q | k | vt | a
    u16* ws = (u16*)d_ws;
    const size_t nX = (size_t)Bc * Lc * Dc;      // 4,194,304
    const size_t nW = (size_t)Dc * Dc;           // 1,048,576
    u16* xb  = ws;
    u16* wqb = xb + nX;
    u16* wkb = wqb + nW;
    u16* wvb = wkb + nW;
    u16* wob = wvb + nW;
    u16* q_w = wob + nW;
    u16* k_w = q_w + nX;
    u16* vt_w = k_w + nX;
    u16* a_w = vt_w + nX;

    cast_bf16<<<dim3(8192), 256, 0, stream>>>(query, Wq, Wk, Wv, Wo,
                                              xb, wqb, wkb, wvb, wob);
    gemm_qkv_bf16<<<dim3(64, 16, 3), 256, 0, stream>>>(xb, wqb, wkb, wvb,
                                                       bq, bk, bv, q_w, k_w, vt_w);
    attn_mfma<<<dim3(512), 512, 0, stream>>>(q_w, k_w, vt_w, a_w);
    gemm_o_bf16<<<dim3(64, 16), 256, 0, stream>>>(a_w, wob, bo, (float*)d_out);
}

// Round 16
// 191.483 us; speedup vs baseline: 1.0371x; 1.0371x over previous
//
#include <hip/hip_runtime.h>

// B=2, L=2048, D=1024, H=16, HD=64.  All matmuls via bf16 MFMA (fp32 accum).
#define Bc 2
#define Lc 2048
#define Dc 1024
#define Hc 16
#define HDc 64
#define LOG2E 1.44269504088896340736f

typedef __bf16 bf16x8 __attribute__((ext_vector_type(8)));
typedef __bf16 bf16x2 __attribute__((ext_vector_type(2)));
typedef float f32x4 __attribute__((ext_vector_type(4)));
typedef unsigned short u16;
typedef unsigned int u32;
typedef unsigned long long u64;

// fp32 -> bf16 round-to-nearest-even
__device__ __forceinline__ u16 f2bf(float x) {
    union { float f; u32 u; } c; c.f = x;
    u32 u = c.u + 0x7fffu + ((c.u >> 16) & 1u);
    return (u16)(u >> 16);
}

// pack two fp32 -> bf16x2 in one u32 (low = a)
__device__ __forceinline__ u32 pkbf(float a, float b) {
#if __has_builtin(__builtin_amdgcn_cvt_pk_bf16_f32)
    union { bf16x2 v; u32 u; } c;
    c.v = __builtin_amdgcn_cvt_pk_bf16_f32(a, b);
    return c.u;
#else
    return (u32)f2bf(a) | ((u32)f2bf(b) << 16);
#endif
}

// raw v_exp_f32 (2^x); libm exp2f adds denormal-range scaffolding we don't
// need (denormal p == 0 for softmax purposes).
__device__ __forceinline__ float fexp2(float x) {
#if __has_builtin(__builtin_amdgcn_exp2f)
    return __builtin_amdgcn_exp2f(x);
#else
    return exp2f(x);
#endif
}

// async global->LDS, 16B/lane. LDS dest = wave-uniform base + lane*16 (m104).
__device__ __forceinline__ void g2l16(const void* g, void* l) {
    __builtin_amdgcn_global_load_lds(
        (const __attribute__((address_space(1))) void*)g,
        (__attribute__((address_space(3))) void*)l, 16, 0, 0);
}

// ---------------------------------------------------------------------------
// cast fp32 -> bf16: query (4096x1024) + Wq/Wk/Wv/Wo (1024x1024 each)
// ---------------------------------------------------------------------------
__global__ __launch_bounds__(256) void cast_bf16(
    const float* __restrict__ x,
    const float* __restrict__ wq, const float* __restrict__ wk,
    const float* __restrict__ wv, const float* __restrict__ wo,
    u16* __restrict__ xb, u16* __restrict__ wqb, u16* __restrict__ wkb,
    u16* __restrict__ wvb, u16* __restrict__ wob)
{
    const int i = blockIdx.x * 256 + threadIdx.x;   // float4 index
    const float* s; u16* d; int off;
    if (i < 1048576) { s = x; d = xb; off = i; }
    else {
        const int j = i - 1048576;
        const int sel = j >> 18;            // 0..3
        off = j & 262143;
        s = sel == 0 ? wq : sel == 1 ? wk : sel == 2 ? wv : wo;
        d = sel == 0 ? wqb : sel == 1 ? wkb : sel == 2 ? wvb : wob;
    }
    const float4 f = ((const float4*)s)[off];
    ushort4 o;
    o.x = f2bf(f.x); o.y = f2bf(f.y); o.z = f2bf(f.z); o.w = f2bf(f.w);
    ((ushort4*)d)[off] = o;
}

// ---------------------------------------------------------------------------
// R15 body: 128(A-rows) x 64(B-rows) tile, BK=64, XOR-swizzled g2l16
// staging. Proven since R4 (refcheck'd). Used by gemm_qkv (R20, 6 blocks/CU).
// ---------------------------------------------------------------------------
__device__ __forceinline__ void gemm_o_body(
    const u16* __restrict__ A, const u16* __restrict__ Bm,
    int row0, int col0, int K,
    f32x4 (&acc)[4][2], u16* As, u16* Bs)
{
    const int tid  = threadIdx.x;
    const int w    = tid >> 6;
    const int lane = tid & 63;
    const int l15  = lane & 15, quad = lane >> 4;
    const int srow = lane >> 3;
    const int sxor = ((lane & 7) ^ srow) << 3;
    const int wm   = (w & 1) << 6, wn = (w >> 1) << 5;   // 2x2 waves over 128x64
    const int l7   = l15 & 7;

    for (int k0 = 0; k0 < K; k0 += 64) {
        __syncthreads();
#pragma unroll
        for (int s = 0; s < 6; ++s) {      // 24 chunks: 16 A (128 rows) + 8 B (64)
            const int c = w * 6 + s;       // 0..23 (wave-uniform branch)
            if (c < 16) {
                const int rb = c * 8;
                g2l16(&A [(size_t)(row0 + rb + srow) * K + k0 + sxor], &As[rb * 64]);
            } else {
                const int rb = (c - 16) * 8;
                g2l16(&Bm[(size_t)(col0 + rb + srow) * K + k0 + sxor], &Bs[rb * 64]);
            }
        }
        __syncthreads();

#pragma unroll
        for (int kk = 0; kk < 2; ++kk) {
            bf16x8 af[4], bf[2];
#pragma unroll
            for (int i = 0; i < 4; ++i)
                af[i] = *(const bf16x8*)&As[(wm + i * 16 + l15) * 64 +
                                            (((kk * 4 + quad) ^ l7) << 3)];
#pragma unroll
            for (int j = 0; j < 2; ++j)
                bf[j] = *(const bf16x8*)&Bs[(wn + j * 16 + l15) * 64 +
                                            (((kk * 4 + quad) ^ l7) << 3)];
#pragma unroll
            for (int i = 0; i < 4; ++i)
#pragma unroll
                for (int j = 0; j < 2; ++j)
                    acc[i][j] = __builtin_amdgcn_mfma_f32_16x16x32_bf16(
                        af[i], bf[j], acc[i][j], 0, 0, 0);
        }
    }
}

// ---------------------------------------------------------------------------
// R22 body: 64(A-rows) x 64(B-rows) tile for gemm_o. LDS 16KB, 16 chunks
// (4/wave), 4 waves 2x2 over the tile, acc[2][2] (16 VGPR -- no spill risk).
// Same swizzle/fragment math; wm=(w&1)<<5, wn=(w>>1)<<5. Grid doubles to
// 1024 = 4 blocks/CU (was 2). NOTE R23: applying this to qkv REGRESSED
// (191.8->198.6): W-staging per MFMA rose ~50%; ladder exhausted there.
// ---------------------------------------------------------------------------
__device__ __forceinline__ void gemm_oo_body(
    const u16* __restrict__ A, const u16* __restrict__ Bm,
    int row0, int col0, int K,
    f32x4 (&acc)[2][2], u16* As, u16* Bs)
{
    const int tid  = threadIdx.x;
    const int w    = tid >> 6;
    const int lane = tid & 63;
    const int l15  = lane & 15, quad = lane >> 4;
    const int srow = lane >> 3;
    const int sxor = ((lane & 7) ^ srow) << 3;
    const int wm   = (w & 1) << 5, wn = (w >> 1) << 5;   // 2x2 waves over 64x64
    const int l7   = l15 & 7;

    for (int k0 = 0; k0 < K; k0 += 64) {
        __syncthreads();
#pragma unroll
        for (int s = 0; s < 4; ++s) {      // 16 chunks: 8 A (64 rows) + 8 B (64)
            const int c = w * 4 + s;       // 0..15 (wave-uniform branch)
            if (c < 8) {
                const int rb = c * 8;
                g2l16(&A [(size_t)(row0 + rb + srow) * K + k0 + sxor], &As[rb * 64]);
            } else {
                const int rb = (c - 8) * 8;
                g2l16(&Bm[(size_t)(col0 + rb + srow) * K + k0 + sxor], &Bs[rb * 64]);
            }
        }
        __syncthreads();

#pragma unroll
        for (int kk = 0; kk < 2; ++kk) {
            bf16x8 af[2], bf[2];
#pragma unroll
            for (int i = 0; i < 2; ++i)
                af[i] = *(const bf16x8*)&As[(wm + i * 16 + l15) * 64 +
                                            (((kk * 4 + quad) ^ l7) << 3)];
#pragma unroll
            for (int j = 0; j < 2; ++j)
                bf[j] = *(const bf16x8*)&Bs[(wn + j * 16 + l15) * 64 +
                                            (((kk * 4 + quad) ^ l7) << 3)];
#pragma unroll
            for (int i = 0; i < 2; ++i)
#pragma unroll
                for (int j = 0; j < 2; ++j)
                    acc[i][j] = __builtin_amdgcn_mfma_f32_16x16x32_bf16(
                        af[i], bf[j], acc[i][j], 0, 0, 0);
        }
    }
}

// ---------------------------------------------------------------------------
// Fused QKV projection, R20 (frozen best): 128x64 tiles, grid (64, 8, 3) =
// 1536 blocks = 6 blocks/CU. LDS 24KB. Same proven gemm_o_body.
//   q/k: SWAPPED (A=W 128 feat, B=X 64 tok): y=feat-tile(8), x=tok-tile(64).
//   v:   NORMAL  (A=X 128 tok, B=Wv 64 feat): tok-tile = x&31,
//        feat-tile = (y<<1)|(x>>5)  (bijective over 32x16).
// q: *(0.125*log2e) folded (exp2-domain softmax).
// R23 (64x64 qkv tiles) REVERTED: 198.6us vs this config's 191.8us.
// ---------------------------------------------------------------------------
__global__ __launch_bounds__(256) void gemm_qkv_bf16(
    const u16* __restrict__ Xb,
    const u16* __restrict__ Wqb, const u16* __restrict__ Wkb, const u16* __restrict__ Wvb,
    const float* __restrict__ bq, const float* __restrict__ bk, const float* __restrict__ bv,
    u16* __restrict__ qo, u16* __restrict__ ko, u16* __restrict__ vto)
{
    __shared__ __attribute__((aligned(16))) u16 As[128 * 64];
    __shared__ __attribute__((aligned(16))) u16 Bs[64 * 64];

    const int z = blockIdx.z;
    const int tid = threadIdx.x;
    const int w = tid >> 6, lane = tid & 63;
    const int l15 = lane & 15, quad = lane >> 4;
    const int wm = (w & 1) << 6, wn = (w >> 1) << 5;

    f32x4 acc[4][2];
#pragma unroll
    for (int i = 0; i < 4; ++i)
#pragma unroll
        for (int j = 0; j < 2; ++j)
#pragma unroll
            for (int r = 0; r < 4; ++r) acc[i][j][r] = 0.0f;

    if (z == 2) {
        // ---- v, NORMAL: A = X (128 tokens), B = Wv (64 features) ----
        const int row0 = (blockIdx.x & 31) << 7;                        // token tile
        const int col0 = ((blockIdx.y << 1) | (blockIdx.x >> 5)) << 6;  // feature tile
        gemm_o_body(Xb, Wvb, row0, col0, Dc, acc, As, Bs);

        const int b = row0 >> 11;              // 128-tile never crosses b
#pragma unroll
        for (int j = 0; j < 2; ++j) {
            const int n = col0 + wn + j * 16 + l15;   // feature
            const float bj = bv[n];
            const int hh = n >> 6, hd = n & 63;
            u16* vbase = vto + (((size_t)(b * Hc + hh) * HDc + hd) << 11);
#pragma unroll
            for (int i = 0; i < 4; ++i) {
                const int l = (row0 + wm + i * 16 + quad * 4) & (Lc - 1);
                uint2 pr;
                pr.x = pkbf(acc[i][j][0] + bj, acc[i][j][1] + bj);
                pr.y = pkbf(acc[i][j][2] + bj, acc[i][j][3] + bj);
                *(uint2*)&vbase[l] = pr;
            }
        }
        return;
    }

    // ---- q/k, SWAPPED: A = W (128 features), B = X (64 tokens) ----
    const u16*   W    = z == 0 ? Wqb : Wkb;
    const float* bias = z == 0 ? bq  : bk;
    u16*         outp = z == 0 ? qo  : ko;
    const int row0 = blockIdx.y << 7;          // feature tile (128)
    const int col0 = blockIdx.x << 6;          // token tile (64)
    gemm_o_body(W, Xb, row0, col0, Dc, acc, As, Bs);

    const float qs = z == 0 ? 0.125f * LOG2E : 1.0f;   // HD^-0.5 * log2(e)
    const int h = (row0 + wm) >> 6;            // head const per quadrant
    float4 b4[4];
#pragma unroll
    for (int i = 0; i < 4; ++i)
        b4[i] = *(const float4*)&bias[row0 + wm + i * 16 + quad * 4];

#pragma unroll
    for (int j = 0; j < 2; ++j) {
        const int tok = col0 + wn + j * 16 + l15;
        const int bb = tok >> 11, ll = tok & (Lc - 1);
        u16* obase = outp + (((size_t)(bb * Hc + h) * Lc + ll) << 6);
#pragma unroll
        for (int i = 0; i < 4; ++i) {
            uint2 pr;
            pr.x = pkbf((acc[i][j][0] + b4[i].x) * qs, (acc[i][j][1] + b4[i].y) * qs);
            pr.y = pkbf((acc[i][j][2] + b4[i].z) * qs, (acc[i][j][3] + b4[i].w) * qs);
            *(uint2*)&obase[i * 16 + quad * 4] = pr;   // hd = i*16+quad*4
        }
    }
}

// ---------------------------------------------------------------------------
// Flash attention, S^T formulation, max-free softmax.  R14 (session best,
// 57us). 8-wave blocks (512 thr), 128 q-rows/block, single-buffer 34KB LDS,
// grid 512. Waves {0-3}: q-sub wq=w&3, key-half 0; waves {4-7}: same q
// rows, key-half 1 (hf=w>>2). Epilogue: 4 wave-pair combine via LDS.
// Falsified alternatives (do not revisit): dbuf staging (R13 69us),
// 64-row grid split (R17 65us), direct-L2 no-LDS (R16 181us), addr hoist
// (R18 72us), KVBLK=256 (R19 72us), fused q+k spill (R21, qkv 101us).
// ---------------------------------------------------------------------------
__global__ __launch_bounds__(512) void attn_mfma(
    const u16* __restrict__ q, const u16* __restrict__ k,
    const u16* __restrict__ vt, u16* __restrict__ out)
{
    // Manually carved LDS: Ks 16KB | Vs 16KB | cl 2KB = 34KB.
    // Epilogue overlays co (32KB floats) on Ks+Vs.
    __shared__ __attribute__((aligned(16))) u16 smem[17408];
    u16* Ks0 = smem;            // [2 d-panels][128 j][32 d] (p*4096 + j*32)
    u16* Vs0 = smem + 8192;     // [4 j-panels][64 d][32 j]  (cp*2048 + d*32)

    const int tid = threadIdx.x;
    const int w = tid >> 6, lane = tid & 63;
    const int l15 = lane & 15, quad = lane >> 4;
    const int bh = blockIdx.x & 31;          // bh fastest: same-bh -> same XCD
    const int qt = blockIdx.x >> 5;          // 0..15
    const int h  = bh & (Hc - 1);
    const int b  = bh >> 4;
    const int l0 = qt << 7;                  // 128 q-rows per block
    const int wq = w & 3;                    // q-row sub-block (32 rows)
    const int hf = w >> 2;                   // fixed 64-key half of staged tile

    const size_t bhs = (size_t)(b * Hc + h) * (Lc * HDc);
    const u16* qb = q  + bhs;
    const u16* kb = k  + bhs;
    const u16* vb = vt + bhs;            // [HD][L]

    bf16x8 qf[2][2];
#pragma unroll
    for (int mt = 0; mt < 2; ++mt) {
        const size_t row = (size_t)(l0 + wq * 32 + mt * 16 + l15) * HDc;
        qf[mt][0] = *(const bf16x8*)&qb[row + quad * 8];
        qf[mt][1] = *(const bf16x8*)&qb[row + 32 + quad * 8];
    }

    const int srow  = lane >> 2;
    const int sunit = lane & 3;
    const int gd = (l15 >> 1) & 3;

    f32x4 oacc[2][4];
    float l_i[2] = {0.0f, 0.0f};
#pragma unroll
    for (int mt = 0; mt < 2; ++mt)
#pragma unroll
        for (int dt = 0; dt < 4; ++dt)
#pragma unroll
            for (int r = 0; r < 4; ++r) oacc[mt][dt][r] = 0.0f;

    for (int kt = 0; kt < Lc; kt += 128) {
        __syncthreads();
        // stage K (16KB: 2 d-panels x 8 groups) + V (16KB: 4 j-panels x 4
        // groups) = 32 chunks, 4 per wave; XOR swizzle on global source.
#pragma unroll
        for (int i = 0; i < 4; ++i) {
            const int c = w * 4 + i;             // 0..31
            if (c < 16) {     // K chunk: row = key j in tile (0..127)
                const int p = c >> 3, g = c & 7;
                const int row = g * 16 + srow;
                g2l16(&kb[(size_t)(kt + row) * HDc + p * 32 +
                          ((sunit ^ ((row >> 1) & 3)) << 3)],
                      &Ks0[p * 4096 + g * 512]);
            } else {          // V chunk: row = d (0..63)
                const int cc = c - 16;
                const int cp = cc >> 2, g = cc & 3;
                const int row = g * 16 + srow;
                g2l16(&vb[(size_t)row * Lc + kt + cp * 32 +
                          ((sunit ^ ((row >> 1) & 3)) << 3)],
                      &Vs0[cp * 2048 + g * 512]);
            }
        }
        __syncthreads();

        // ---- one 64-key half (hf fixed per wave; R12 inner body) ----
        f32x4 st[2][4];
        __builtin_amdgcn_s_setprio(1);
#pragma unroll
        for (int t = 0; t < 4; ++t) {
            const int j   = (hf * 4 + t) * 16 + l15;
            const int off = j * 32 + ((quad ^ gd) << 3);
            const bf16x8 kf0 = *(const bf16x8*)&Ks0[off];
            const bf16x8 kf1 = *(const bf16x8*)&Ks0[4096 + off];
#pragma unroll
            for (int mt = 0; mt < 2; ++mt) {
                f32x4 z = {0.0f, 0.0f, 0.0f, 0.0f};
                z = __builtin_amdgcn_mfma_f32_16x16x32_bf16(kf0, qf[mt][0], z, 0, 0, 0);
                st[mt][t] = __builtin_amdgcn_mfma_f32_16x16x32_bf16(kf1, qf[mt][1], z, 0, 0, 0);
            }
        }
        __builtin_amdgcn_s_setprio(0);

        u32 pk[2][4][2];
#pragma unroll
        for (int mt = 0; mt < 2; ++mt) {
            f32x4 s4 = {0.0f, 0.0f, 0.0f, 0.0f};
#pragma unroll
            for (int t = 0; t < 4; ++t) {
                f32x4 p;
#pragma unroll
                for (int r = 0; r < 4; ++r) p[r] = fexp2(st[mt][t][r]);
                s4 += p;
                pk[mt][t][0] = pkbf(p[0], p[1]);
                pk[mt][t][1] = pkbf(p[2], p[3]);
            }
            l_i[mt] += s4[0] + s4[1] + s4[2] + s4[3];
        }

        __builtin_amdgcn_s_setprio(1);
#pragma unroll
        for (int cpl = 0; cpl < 2; ++cpl) {
            const int cp = hf * 2 + cpl;     // V panel (j-chunks 2cp,2cp+1)
            union { bf16x8 v; u32 uw[4]; } pf0, pf1;
            pf0.uw[0] = pk[0][2 * cpl][0];     pf0.uw[1] = pk[0][2 * cpl][1];
            pf0.uw[2] = pk[0][2 * cpl + 1][0]; pf0.uw[3] = pk[0][2 * cpl + 1][1];
            pf1.uw[0] = pk[1][2 * cpl][0];     pf1.uw[1] = pk[1][2 * cpl][1];
            pf1.uw[2] = pk[1][2 * cpl + 1][0]; pf1.uw[3] = pk[1][2 * cpl + 1][1];
#pragma unroll
            for (int dt = 0; dt < 4; ++dt) {
                const int base = cp * 2048 + (dt * 16 + l15) * 32 + ((quad & 1) << 2);
                union { bf16x8 v; u64 d[2]; } vf;
                vf.d[0] = *(const u64*)&Vs0[base + (((quad >> 1) ^ gd) << 3)];
                vf.d[1] = *(const u64*)&Vs0[base + (((2 + (quad >> 1)) ^ gd) << 3)];
                oacc[0][dt] = __builtin_amdgcn_mfma_f32_16x16x32_bf16(
                    vf.v, pf0.v, oacc[0][dt], 0, 0, 0);
                oacc[1][dt] = __builtin_amdgcn_mfma_f32_16x16x32_bf16(
                    vf.v, pf1.v, oacc[1][dt], 0, 0, 0);
            }
        }
        __builtin_amdgcn_s_setprio(0);
    }

    // ---- cross-pair combine: waves 4-7 hand their key-half partials to
    // waves 0-3 (same q rows, other 64-key half). Max-free softmax => plain
    // elementwise add. co overlays Ks+Vs (32KB exactly: 32 floats x 256
    // lanes, [idx][base] stride-256 = conflict-free b32); cl = 2KB tail.
    __syncthreads();                         // all waves done with tile LDS
    float* co = (float*)smem;
    float* cl = (float*)(smem + 16384);
    if (w >= 4) {
        const int base = (w - 4) * 64 + lane;          // 0..255
#pragma unroll
        for (int mt = 0; mt < 2; ++mt)
#pragma unroll
            for (int dt = 0; dt < 4; ++dt)
#pragma unroll
                for (int r = 0; r < 4; ++r)
                    co[(mt * 16 + dt * 4 + r) * 256 + base] = oacc[mt][dt][r];
        cl[base]       = l_i[0];
        cl[256 + base] = l_i[1];
    }
    __syncthreads();
    if (w >= 4) return;
    {
        const int base = w * 64 + lane;                // 0..255
#pragma unroll
        for (int mt = 0; mt < 2; ++mt)
#pragma unroll
            for (int dt = 0; dt < 4; ++dt)
#pragma unroll
                for (int r = 0; r < 4; ++r)
                    oacc[mt][dt][r] += co[(mt * 16 + dt * 4 + r) * 256 + base];
        l_i[0] += cl[base];
        l_i[1] += cl[256 + base];
    }

#pragma unroll
    for (int mt = 0; mt < 2; ++mt) {
        float l = l_i[mt];
        l += __shfl_xor(l, 16);
        l += __shfl_xor(l, 32);
        const float inv = 1.0f / l;
        const int lrow = l0 + wq * 32 + mt * 16 + l15;
        u16* ob = out + ((size_t)(b * Lc + lrow)) * Dc + h * HDc;
#pragma unroll
        for (int dt = 0; dt < 4; ++dt) {
            uint2 pr;
            pr.x = pkbf(oacc[mt][dt][0] * inv, oacc[mt][dt][1] * inv);
            pr.y = pkbf(oacc[mt][dt][2] * inv, oacc[mt][dt][3] * inv);
            *(uint2*)&ob[dt * 16 + quad * 4] = pr;
        }
    }
}

// ---------------------------------------------------------------------------
// Output projection, R22 (frozen best): 64(feature) x 64(token) tiles, grid
// (64, 16) = 1024 blocks = 4 blocks/CU. LDS 16KB. SWAPPED: regs run along
// features -> float4 contiguous stores into row-major (B,L,D) fp32.
// ---------------------------------------------------------------------------
__global__ __launch_bounds__(256) void gemm_o_bf16(
    const u16* __restrict__ Ab, const u16* __restrict__ Wob,
    const float* __restrict__ bo, float* __restrict__ out)
{
    __shared__ __attribute__((aligned(16))) u16 As[64 * 64];
    __shared__ __attribute__((aligned(16))) u16 Bs[64 * 64];
    const int row0 = blockIdx.y << 6;          // feature tile (64)
    const int col0 = blockIdx.x << 6;          // token tile (64)

    f32x4 acc[2][2];
#pragma unroll
    for (int i = 0; i < 2; ++i)
#pragma unroll
        for (int j = 0; j < 2; ++j)
#pragma unroll
            for (int r = 0; r < 4; ++r) acc[i][j][r] = 0.0f;

    gemm_oo_body(Wob, Ab, row0, col0, Dc, acc, As, Bs);

    const int tid = threadIdx.x;
    const int w = tid >> 6, lane = tid & 63;
    const int l15 = lane & 15, quad = lane >> 4;
    const int wm = (w & 1) << 5, wn = (w >> 1) << 5;

    float4 b4[2];
#pragma unroll
    for (int i = 0; i < 2; ++i)
        b4[i] = *(const float4*)&bo[row0 + wm + i * 16 + quad * 4];

#pragma unroll
    for (int j = 0; j < 2; ++j) {
        const int tok = col0 + wn + j * 16 + l15;
        float* obase = out + (size_t)tok * Dc + row0 + wm;
#pragma unroll
        for (int i = 0; i < 2; ++i) {
            float4 o;
            o.x = acc[i][j][0] + b4[i].x; o.y = acc[i][j][1] + b4[i].y;
            o.z = acc[i][j][2] + b4[i].z; o.w = acc[i][j][3] + b4[i].w;
            *(float4*)&obase[i * 16 + quad * 4] = o;
        }
    }
}

extern "C" void kernel_launch(void* const* d_in, const int* in_sizes, int n_in,
                              void* d_out, int out_size, void* d_ws, size_t ws_size,
                              hipStream_t stream)
{
    const float* query = (const float*)d_in[0];
    const float* Wq = (const float*)d_in[1];
    const float* bq = (const float*)d_in[2];
    const float* Wk = (const float*)d_in[3];
    const float* bk = (const float*)d_in[4];
    const float* Wv = (const float*)d_in[5];
    const float* bv = (const float*)d_in[6];
    const float* Wo = (const float*)d_in[7];
    const float* bo = (const float*)d_in[8];

    // ws layout (u16 elems): xb 4.19M | wq/wk/wv/wo 1.05M ea | q | k | vt | a
    u16* ws = (u16*)d_ws;
    const size_t nX = (size_t)Bc * Lc * Dc;      // 4,194,304
    const size_t nW = (size_t)Dc * Dc;           // 1,048,576
    u16* xb  = ws;
    u16* wqb = xb + nX;
    u16* wkb = wqb + nW;
    u16* wvb = wkb + nW;
    u16* wob = wvb + nW;
    u16* q_w = wob + nW;
    u16* k_w = q_w + nX;
    u16* vt_w = k_w + nX;
    u16* a_w = vt_w + nX;

    cast_bf16<<<dim3(8192), 256, 0, stream>>>(query, Wq, Wk, Wv, Wo,
                                              xb, wqb, wkb, wvb, wob);
    gemm_qkv_bf16<<<dim3(64, 8, 3), 256, 0, stream>>>(xb, wqb, wkb, wvb,
                                                      bq, bk, bv, q_w, k_w, vt_w);
    attn_mfma<<<dim3(512), 512, 0, stream>>>(q_w, k_w, vt_w, a_w);
    gemm_o_bf16<<<dim3(64, 16), 256, 0, stream>>>(a_w, wob, bo, (float*)d_out);
}